// Round 2
// baseline (1083.265 us; speedup 1.0000x reference)
//
#include <hip/hip_runtime.h>
#include <stdint.h>

#define B 8192
#define T 512
#define K 24
#define GPB 8
#define BLK (K * GPB)   // 192 threads = 3 waves

// ---------------------------------------------------------------------------
// Forward Viterbi. One lane per (batch, tag-column): 24 lanes/batch, 8 batches
// per 192-thread block. Alpha double-buffered in LDS. Tournament argmax
// (depth ~10) with exact first-index tie-break: every merge compares an
// earlier-index range vs a later one and keeps the earlier on ties (vb > va).
// WS=true: backpointers packed to d_ws [B][T][K] bytes, tags to d_ws+100MB.
// WS=false: bp bytes embedded at out[b][t] words 18..23, last_tag at rec0[18].
// ---------------------------------------------------------------------------
template<bool WS>
__global__ __launch_bounds__(BLK) void crf_forward(
    const float* __restrict__ inp,    // [B, T, K]
    const float* __restrict__ trans,  // [K, K] (prev i -> cur j)
    float* __restrict__ out,
    uint8_t* __restrict__ bp_ws,
    uint8_t* __restrict__ tag_ws)
{
    __shared__ float alpha[2][GPB][K];

    const int tid = threadIdx.x;
    const int g   = tid / K;
    const int l   = tid - g * K;            // tag column owned by this lane
    const int b   = blockIdx.x * GPB + g;   // 1024 blocks * 8 = 8192

    float tc[K];                            // transition column l
#pragma unroll
    for (int i = 0; i < K; ++i) tc[i] = trans[i * K + l];

    const float* ebase = inp + (size_t)b * T * K;
    uint32_t*    obw   = (uint32_t*)out + (size_t)b * T * K;
    uint8_t*     bpb   = WS ? (bp_ws + (size_t)b * T * K) : nullptr;

    alpha[0][g][l] = ebase[l];              // t = 0
    __syncthreads();

    float em = ebase[K + l];                // emission for t = 1 (prefetched)
    int cur = 0;
#pragma unroll 1
    for (int t = 1; t < T; ++t) {
        int tn = (t + 1 < T) ? (t + 1) : t;
        float em_next = ebase[(size_t)tn * K + l];

        float a[K];
#pragma unroll
        for (int c = 0; c < 6; ++c) {
            float4 v = *(const float4*)&alpha[cur][g][4 * c];
            a[4*c] = v.x; a[4*c+1] = v.y; a[4*c+2] = v.z; a[4*c+3] = v.w;
        }
        float s[K];
#pragma unroll
        for (int i = 0; i < K; ++i) s[i] = a[i] + tc[i];

        // tournament argmax (first-index tie-break)
        float v0[12]; int i0[12];
#pragma unroll
        for (int p = 0; p < 12; ++p) {
            bool gt = s[2*p+1] > s[2*p];
            v0[p] = gt ? s[2*p+1] : s[2*p];
            i0[p] = gt ? 2*p+1 : 2*p;
        }
        float v1[6]; int i1[6];
#pragma unroll
        for (int p = 0; p < 6; ++p) {
            bool gt = v1[0], dummy; (void)dummy;
            gt = v0[2*p+1] > v0[2*p];
            v1[p] = gt ? v0[2*p+1] : v0[2*p];
            i1[p] = gt ? i0[2*p+1] : i0[2*p];
        }
        float v2[3]; int i2[3];
#pragma unroll
        for (int p = 0; p < 3; ++p) {
            bool gt = v1[2*p+1] > v1[2*p];
            v2[p] = gt ? v1[2*p+1] : v1[2*p];
            i2[p] = gt ? i1[2*p+1] : i1[2*p];
        }
        bool g01 = v2[1] > v2[0];
        float vx = g01 ? v2[1] : v2[0];
        int   ix = g01 ? i2[1] : i2[0];
        bool g2  = v2[2] > vx;
        float win = g2 ? v2[2] : vx;
        int   p   = g2 ? i2[2] : ix;

        alpha[cur ^ 1][g][l] = win + em;

        if (WS) bpb[(size_t)t * K + l] = (uint8_t)p;
        else    *((uint8_t*)(obw + (size_t)t * K + 18) + l) = (uint8_t)p;

        em = em_next;
        __syncthreads();
        cur ^= 1;
    }

    if (l == 0) {   // last_tag = first-index argmax of final alpha
        float m = alpha[cur][g][0]; int pbest = 0;
#pragma unroll
        for (int i = 1; i < K; ++i) {
            float v = alpha[cur][g][i];
            bool gt = v > m;
            m = gt ? v : m;
            pbest = gt ? i : pbest;
        }
        if (WS) tag_ws[(size_t)b * T + (T - 1)] = (uint8_t)pbest;
        else    obw[18] = (uint32_t)pbest;
    }
}

// ---------------------------------------------------------------------------
// Chase: follow backpointers, 1 thread/batch. 4-slot x 8-step register
// pipeline (~24 steps / ~4.7MB chip-wide in flight) to cover HBM latency.
// Writes tag for every t (WS: byte to tag_ws; else u32 to rec[t] word 18).
// ---------------------------------------------------------------------------
template<bool WS>
__global__ __launch_bounds__(64) void crf_chase(
    float* __restrict__ out,
    const uint8_t* __restrict__ bp_ws,
    uint8_t* __restrict__ tag_ws)
{
    const int b = blockIdx.x * 64 + threadIdx.x;
    uint32_t*       obw = (uint32_t*)out + (size_t)b * T * K;
    const uint8_t*  bpb = WS ? (bp_ws + (size_t)b * T * K) : nullptr;
    uint8_t*        tgb = WS ? (tag_ws + (size_t)b * T) : nullptr;

    uint32_t w[4][8][6];

#define LOADG(GG, SLOT) do {                                                  \
    int gg_ = (GG);                                                           \
    if (gg_ < 64) {                                                           \
      _Pragma("unroll")                                                       \
      for (int q_ = 0; q_ < 8; ++q_) {                                        \
        int u_ = 511 - 8 * gg_ - q_;                                          \
        const uint32_t* r_;                                                   \
        if (WS) r_ = (const uint32_t*)(bpb + (size_t)u_ * K);                 \
        else    r_ = obw + (size_t)u_ * K + 18;                               \
        *(uint2*)&w[SLOT][q_][0] = *(const uint2*)(r_);                       \
        *(uint2*)&w[SLOT][q_][2] = *(const uint2*)(r_ + 2);                   \
        *(uint2*)&w[SLOT][q_][4] = *(const uint2*)(r_ + 4);                   \
      }                                                                       \
    }                                                                         \
  } while (0)

#define PROCG(GG, SLOT) do {                                                  \
    int gg_ = (GG);                                                           \
    _Pragma("unroll")                                                         \
    for (int q_ = 0; q_ < 8; ++q_) {                                          \
      int u_ = 511 - 8 * gg_ - q_;                                            \
      if (u_ > 0) {                                                           \
        int idx_ = cur >> 2;                                                  \
        uint32_t wA_ = (idx_ & 1) ? w[SLOT][q_][1] : w[SLOT][q_][0];          \
        uint32_t wB_ = (idx_ & 1) ? w[SLOT][q_][3] : w[SLOT][q_][2];          \
        uint32_t wC_ = (idx_ & 1) ? w[SLOT][q_][5] : w[SLOT][q_][4];          \
        uint32_t wAB_ = (idx_ & 2) ? wB_ : wA_;                               \
        uint32_t wd_  = (idx_ & 4) ? wC_ : wAB_;                              \
        int nxt_ = (int)((wd_ >> ((cur & 3) * 8)) & 0xFF);                    \
        if (WS) tgb[u_] = (uint8_t)cur;                                       \
        else    obw[(size_t)u_ * K + 18] = (uint32_t)cur;                     \
        cur = nxt_;                                                           \
      } else {                                                                \
        if (WS) tgb[0] = (uint8_t)cur;                                        \
        else    obw[18] = (uint32_t)cur;                                      \
      }                                                                       \
    }                                                                         \
  } while (0)

    int cur;
    if (WS) cur = (int)tgb[T - 1];
    else    cur = (int)obw[18];

    LOADG(0, 0); LOADG(1, 1); LOADG(2, 2); LOADG(3, 3);

#pragma unroll 1
    for (int base = 0; base < 60; base += 4) {
        PROCG(base + 0, 0); LOADG(base + 4, 0);
        PROCG(base + 1, 1); LOADG(base + 5, 1);
        PROCG(base + 2, 2); LOADG(base + 6, 2);
        PROCG(base + 3, 3); LOADG(base + 7, 3);
    }
    PROCG(60, 0); PROCG(61, 1); PROCG(62, 2); PROCG(63, 3);
#undef LOADG
#undef PROCG
}

// ---------------------------------------------------------------------------
// One-hot scatter: one thread per (b,t), fully coalesced 96B record writes.
// ---------------------------------------------------------------------------
template<bool WS>
__global__ __launch_bounds__(256) void crf_onehot(
    float* __restrict__ out, const uint8_t* __restrict__ tag_ws)
{
    const size_t idx = (size_t)blockIdx.x * 256 + threadIdx.x;  // < B*T
    uint32_t* rec = (uint32_t*)out + idx * K;
    int tag;
    if (WS) tag = (int)tag_ws[idx];
    else    tag = (int)rec[18];
#pragma unroll
    for (int c = 0; c < 6; ++c) {
        uint4 v;
        v.x = (tag == 4*c+0) ? 0x3F800000u : 0u;
        v.y = (tag == 4*c+1) ? 0x3F800000u : 0u;
        v.z = (tag == 4*c+2) ? 0x3F800000u : 0u;
        v.w = (tag == 4*c+3) ? 0x3F800000u : 0u;
        *(uint4*)(rec + 4*c) = v;
    }
}

extern "C" void kernel_launch(void* const* d_in, const int* in_sizes, int n_in,
                              void* d_out, int out_size, void* d_ws, size_t ws_size,
                              hipStream_t stream) {
    const float* inp   = (const float*)d_in[0];   // [8192, 512, 24]
    const float* trans = (const float*)d_in[1];   // [24, 24]
    float*       out   = (float*)d_out;           // [8192, 512, 24]

    const size_t need = (size_t)B * T * K + (size_t)B * T;  // bp + tags
    if (ws_size >= need) {
        uint8_t* bp = (uint8_t*)d_ws;
        uint8_t* tg = (uint8_t*)d_ws + (size_t)B * T * K;
        crf_forward<true><<<B / GPB, BLK, 0, stream>>>(inp, trans, out, bp, tg);
        crf_chase<true><<<B / 64, 64, 0, stream>>>(out, bp, tg);
        crf_onehot<true><<<(B * T) / 256, 256, 0, stream>>>(out, tg);
    } else {
        crf_forward<false><<<B / GPB, BLK, 0, stream>>>(inp, trans, out, nullptr, nullptr);
        crf_chase<false><<<B / 64, 64, 0, stream>>>(out, nullptr, nullptr);
        crf_onehot<false><<<(B * T) / 256, 256, 0, stream>>>(out, nullptr);
    }
}